// Round 1
// baseline (733.833 us; speedup 1.0000x reference)
//
#include <hip/hip_runtime.h>

#define VOCAB 32000
#define EMB   512
#define ENC2  1024
#define DECH  1024
#define ATTN  512
#define BB    64
#define SS    128
#define KXH   2560   // [emb 512 | ctx 1024 | hid 1024]
#define KOI   2560   // [nh 1024 | ctx 1024 | emb 512]

typedef __attribute__((ext_vector_type(4))) float  f32x4;
typedef __attribute__((ext_vector_type(8))) __bf16 bf16x8;

// ws layout (bytes)
#define OFF_DP 0           // dec_proj   64x512  f32   (131072)
#define OFF_SC 131072      // scores     64x128  f32   (32768)
#define OFF_GP 163840      // gate part  4x64x4096 f32 (4194304)
#define OFF_XH 4358144     // xh  bf16   64x2560       (327680)
#define OFF_OI 4685824     // out_in bf16 64x2560      (327680)
#define OFF_WE 5013504     // W_enc bf16 512x1024      (1048576)

static __device__ __forceinline__ bf16x8 cvt8(const float* p) {
    f32x4 a = *(const f32x4*)p;
    f32x4 b = *(const f32x4*)(p + 4);
    bf16x8 t;
    t[0] = (__bf16)a[0]; t[1] = (__bf16)a[1]; t[2] = (__bf16)a[2]; t[3] = (__bf16)a[3];
    t[4] = (__bf16)b[0]; t[5] = (__bf16)b[1]; t[6] = (__bf16)b[2]; t[7] = (__bf16)b[3];
    return t;
}

static __device__ __forceinline__ f32x4 mfma16(bf16x8 a, bf16x8 b, f32x4 c) {
    return __builtin_amdgcn_mfma_f32_16x16x32_bf16(a, b, c, 0, 0, 0);
}

// ---- W_enc f32 -> bf16 (once per launch) -------------------------------
__global__ void k_cvt_we(const float* __restrict__ We, __bf16* __restrict__ we16) {
    int g = blockIdx.x * 256 + threadIdx.x;      // 65536 threads x 8 elems
    int base = g * 8;
    *(bf16x8*)(we16 + base) = cvt8(We + base);
}

// ---- embedding gather + hidden cvt -------------------------------------
__global__ void k_prep(const int* __restrict__ tok, const float* __restrict__ hidden,
                       const float* __restrict__ emb,
                       __bf16* __restrict__ xh, __bf16* __restrict__ oi) {
    int b = blockIdx.x, t = threadIdx.x;
    int tk = tok[b];
    #pragma unroll
    for (int j = 0; j < 2; ++j) {
        int e = t + 256 * j;
        float v = (tk == 0) ? 0.f : emb[tk * EMB + e];
        __bf16 h = (__bf16)v;
        xh[b * KXH + e] = h;                 // x = [emb | ctx]
        oi[b * KOI + 2048 + e] = h;          // out_in = [nh | ctx | emb]
    }
    #pragma unroll
    for (int j = 0; j < 4; ++j) {
        int hidx = t + 256 * j;
        xh[b * KXH + 1536 + hidx] = (__bf16)hidden[b * DECH + hidx];
    }
}

// ---- dec_proj = hidden @ W_dec^T  [64,512] -----------------------------
__global__ void k_decproj(const float* __restrict__ hidden, const float* __restrict__ Wd,
                          float* __restrict__ dp) {
    int g = blockIdx.x * 256 + threadIdx.x;  // 32768
    int b = g >> 9, a = g & 511;
    const float* h = hidden + b * DECH;
    const float* w = Wd + a * DECH;
    float acc = 0.f;
    #pragma unroll 4
    for (int k = 0; k < DECH; ++k) acc += h[k] * w[k];
    dp[b * ATTN + a] = acc;
}

// ---- fused scores: tanh(enc@We^T + dp) . v  -> atomic scores[b][s] -----
__global__ __launch_bounds__(256) void k_scores(const float* __restrict__ enc,
                                                const __bf16* __restrict__ we16,
                                                const float* __restrict__ dp,
                                                const float* __restrict__ v,
                                                float* __restrict__ sc) {
    int t = threadIdx.x;
    int w = t >> 6, l = t & 63, lo = l & 15, hi = l >> 4;
    int r0 = blockIdx.x * 16;                 // 16 rows (one s, 16 b's), 512 blocks
    int cb = w * 128;                         // wave col strip
    f32x4 acc[8];
    #pragma unroll
    for (int f = 0; f < 8; ++f) acc[f] = (f32x4){0.f, 0.f, 0.f, 0.f};

    const float* arow = enc + (r0 + lo) * ENC2 + hi * 8;
    for (int k0 = 0; k0 < ENC2; k0 += 32) {
        bf16x8 af = cvt8(arow + k0);
        #pragma unroll
        for (int f = 0; f < 8; ++f) {
            bf16x8 bf = *(const bf16x8*)(we16 + (cb + f * 16 + lo) * ENC2 + k0 + hi * 8);
            acc[f] = mfma16(af, bf, acc[f]);
        }
    }
    // epilogue: p[row] = sum_c v[c]*tanh(acc + dp[b][c])
    int s_ = r0 >> 6;
    float p[4] = {0.f, 0.f, 0.f, 0.f};
    #pragma unroll
    for (int f = 0; f < 8; ++f) {
        int c = cb + f * 16 + lo;
        float vv = v[c];
        #pragma unroll
        for (int ri = 0; ri < 4; ++ri) {
            int r = r0 + hi * 4 + ri;
            int b = r & 63;
            p[ri] += vv * tanhf(acc[f][ri] + dp[b * ATTN + c]);
        }
    }
    #pragma unroll
    for (int m = 1; m < 16; m <<= 1) {
        #pragma unroll
        for (int ri = 0; ri < 4; ++ri) p[ri] += __shfl_xor(p[ri], m);
    }
    if (lo == 0) {
        #pragma unroll
        for (int ri = 0; ri < 4; ++ri) {
            int r = r0 + hi * 4 + ri;
            atomicAdd(&sc[(r & 63) * SS + s_], p[ri]);
        }
    }
}

// ---- masked softmax over S per b ---------------------------------------
__global__ void k_softmax(const float* __restrict__ sc, const int* __restrict__ mask,
                          float* __restrict__ attn) {
    int b = blockIdx.x, l = threadIdx.x;      // 64 threads
    float s0 = sc[b * SS + l], s1 = sc[b * SS + 64 + l];
    if (mask[b * SS + l] == 0)      s0 = -3.0e38f;
    if (mask[b * SS + 64 + l] == 0) s1 = -3.0e38f;
    float m = fmaxf(s0, s1);
    #pragma unroll
    for (int x = 32; x >= 1; x >>= 1) m = fmaxf(m, __shfl_xor(m, x));
    float e0 = expf(s0 - m), e1 = expf(s1 - m);
    float sum = e0 + e1;
    #pragma unroll
    for (int x = 32; x >= 1; x >>= 1) sum += __shfl_xor(sum, x);
    float inv = 1.f / sum;
    attn[b * SS + l] = e0 * inv;
    attn[b * SS + 64 + l] = e1 * inv;
}

// ---- context[b,e] = sum_s attn[b,s]*enc[s,b,e] -------------------------
__global__ void k_context(const float* __restrict__ enc, const float* __restrict__ attn,
                          __bf16* __restrict__ xh, __bf16* __restrict__ oi) {
    int b = blockIdx.x, t = threadIdx.x;
    __shared__ float w[SS];
    if (t < SS) w[t] = attn[b * SS + t];
    __syncthreads();
    float acc[4] = {0.f, 0.f, 0.f, 0.f};
    for (int s = 0; s < SS; ++s) {
        float ws = w[s];
        const float* e = enc + (s * BB + b) * ENC2;
        #pragma unroll
        for (int j = 0; j < 4; ++j) acc[j] += ws * e[t + 256 * j];
    }
    #pragma unroll
    for (int j = 0; j < 4; ++j) {
        int e = t + 256 * j;
        __bf16 h = (__bf16)acc[j];
        xh[b * KXH + 512 + e] = h;
        oi[b * KOI + 1024 + e] = h;
    }
}

// ---- gates GEMM: [64,4096] = xh @ [W_ih|W_hh]^T, split-K=4 -------------
__global__ __launch_bounds__(256) void k_gates(const __bf16* __restrict__ xh,
                                               const float* __restrict__ Wih,
                                               const float* __restrict__ Whh,
                                               float* __restrict__ gp) {
    int bx = blockIdx.x, ks = blockIdx.y;
    int t = threadIdx.x, w = t >> 6, l = t & 63, lo = l & 15, hi = l >> 4;
    int n = bx * 64 + w * 16 + lo;
    f32x4 acc[4];
    #pragma unroll
    for (int m = 0; m < 4; ++m) acc[m] = (f32x4){0.f, 0.f, 0.f, 0.f};
    int kend = ks * 640 + 640;
    for (int k0 = ks * 640; k0 < kend; k0 += 32) {
        int k = k0 + hi * 8;
        const float* bp = (k0 < 1536) ? (Wih + n * 1536 + k) : (Whh + n * 1024 + (k - 1536));
        bf16x8 bf = cvt8(bp);
        #pragma unroll
        for (int m = 0; m < 4; ++m) {
            bf16x8 af = *(const bf16x8*)(xh + (m * 16 + lo) * KXH + k);
            acc[m] = mfma16(af, bf, acc[m]);
        }
    }
    float* out = gp + ks * (BB * 4096);
    #pragma unroll
    for (int m = 0; m < 4; ++m)
        #pragma unroll
        for (int ri = 0; ri < 4; ++ri) {
            int row = m * 16 + hi * 4 + ri;
            out[row * 4096 + n] = acc[m][ri];
        }
}

// ---- LSTM pointwise ----------------------------------------------------
__global__ void k_lstm(const float* __restrict__ gp, const float* __restrict__ bih,
                       const float* __restrict__ bhh, const float* __restrict__ cell,
                       float* __restrict__ nh_out, float* __restrict__ nc_out,
                       __bf16* __restrict__ oi) {
    int b = blockIdx.x, t = threadIdx.x;
    #pragma unroll
    for (int j = 0; j < 4; ++j) {
        int h = t + 256 * j;
        float gi = 0.f, gf = 0.f, gg = 0.f, go = 0.f;
        #pragma unroll
        for (int ks = 0; ks < 4; ++ks) {
            const float* g = gp + ks * (BB * 4096) + b * 4096;
            gi += g[h]; gf += g[1024 + h]; gg += g[2048 + h]; go += g[3072 + h];
        }
        gi += bih[h] + bhh[h];
        gf += bih[1024 + h] + bhh[1024 + h];
        gg += bih[2048 + h] + bhh[2048 + h];
        go += bih[3072 + h] + bhh[3072 + h];
        float i_ = 1.f / (1.f + expf(-gi));
        float f_ = 1.f / (1.f + expf(-gf));
        float o_ = 1.f / (1.f + expf(-go));
        float g_ = tanhf(gg);
        float nc = f_ * cell[b * DECH + h] + i_ * g_;
        float nh = o_ * tanhf(nc);
        nc_out[b * DECH + h] = nc;
        nh_out[b * DECH + h] = nh;
        oi[b * KOI + h] = (__bf16)nh;
    }
}

// ---- output GEMM: [64,32000] = out_in @ W_out^T + b_out ----------------
__global__ __launch_bounds__(256) void k_out(const __bf16* __restrict__ oi,
                                             const float* __restrict__ Wo,
                                             const float* __restrict__ bo,
                                             float* __restrict__ out) {
    int bx = blockIdx.x;
    int t = threadIdx.x, w = t >> 6, l = t & 63, lo = l & 15, hi = l >> 4;
    int n = bx * 64 + w * 16 + lo;
    f32x4 acc[4];
    #pragma unroll
    for (int m = 0; m < 4; ++m) acc[m] = (f32x4){0.f, 0.f, 0.f, 0.f};
    const float* wrow = Wo + (long)n * KOI;
    for (int k0 = 0; k0 < KOI; k0 += 32) {
        int k = k0 + hi * 8;
        bf16x8 bf = cvt8(wrow + k);
        #pragma unroll
        for (int m = 0; m < 4; ++m) {
            bf16x8 af = *(const bf16x8*)(oi + (m * 16 + lo) * KOI + k);
            acc[m] = mfma16(af, bf, acc[m]);
        }
    }
    float bb = bo[n];
    #pragma unroll
    for (int m = 0; m < 4; ++m)
        #pragma unroll
        for (int ri = 0; ri < 4; ++ri) {
            int row = m * 16 + hi * 4 + ri;
            out[row * VOCAB + n] = acc[m][ri] + bb;
        }
}

extern "C" void kernel_launch(void* const* d_in, const int* in_sizes, int n_in,
                              void* d_out, int out_size, void* d_ws, size_t ws_size,
                              hipStream_t stream) {
    const int*   tok    = (const int*)d_in[0];
    const float* hidden = (const float*)d_in[1];
    const float* cell   = (const float*)d_in[2];
    const float* enc    = (const float*)d_in[3];
    const int*   mask   = (const int*)d_in[4];
    const float* emb    = (const float*)d_in[5];
    const float* We     = (const float*)d_in[6];
    const float* Wd     = (const float*)d_in[7];
    const float* v      = (const float*)d_in[8];
    const float* Wih    = (const float*)d_in[9];
    const float* Whh    = (const float*)d_in[10];
    const float* bih    = (const float*)d_in[11];
    const float* bhh    = (const float*)d_in[12];
    const float* Wo     = (const float*)d_in[13];
    const float* bo     = (const float*)d_in[14];

    char* ws = (char*)d_ws;
    float*  dp   = (float*)(ws + OFF_DP);
    float*  sc   = (float*)(ws + OFF_SC);
    float*  gp   = (float*)(ws + OFF_GP);
    __bf16* xh   = (__bf16*)(ws + OFF_XH);
    __bf16* oi   = (__bf16*)(ws + OFF_OI);
    __bf16* we16 = (__bf16*)(ws + OFF_WE);

    float* out_logits = (float*)d_out;                 // [64,32000]
    float* nh   = out_logits + BB * VOCAB;             // [64,1024]
    float* nc   = nh + BB * DECH;                      // [64,1024]
    float* attn = nc + BB * DECH;                      // [64,128]

    hipMemsetAsync(sc, 0, BB * SS * sizeof(float), stream);
    k_cvt_we<<<256, 256, 0, stream>>>(We, we16);
    k_prep<<<BB, 256, 0, stream>>>(tok, hidden, emb, xh, oi);
    k_decproj<<<128, 256, 0, stream>>>(hidden, Wd, dp);
    k_scores<<<512, 256, 0, stream>>>(enc, we16, dp, v, sc);
    k_softmax<<<BB, 64, 0, stream>>>(sc, mask, attn);
    k_context<<<BB, 256, 0, stream>>>(enc, attn, xh, oi);
    dim3 g2(64, 4);
    k_gates<<<g2, 256, 0, stream>>>(xh, Wih, Whh, gp);
    k_lstm<<<BB, 256, 0, stream>>>(gp, bih, bhh, cell, nh, nc, oi);
    k_out<<<500, 256, 0, stream>>>(oi, Wo, bo, out_logits);
}

// Round 2
// 683.768 us; speedup vs baseline: 1.0732x; 1.0732x over previous
//
#include <hip/hip_runtime.h>

#define VOCAB 32000
#define EMB   512
#define ENC2  1024
#define DECH  1024
#define ATTN  512
#define BB    64
#define SS    128
#define KXH   2560   // [emb 512 | ctx 1024 | hid 1024]
#define KOI   2560   // [nh 1024 | ctx 1024 | emb 512]

typedef __attribute__((ext_vector_type(4))) float  f32x4;
typedef __attribute__((ext_vector_type(8))) __bf16 bf16x8;

// ws layout (bytes)
#define OFF_SC  0          // scores   64x128 f32      (32768)
#define OFF_CTX 32768      // context  64x1024 f32     (262144)
#define OFF_GP  294912     // gate part 4x64x4096 f32  (4194304)
#define OFF_XH  4489216    // xh  bf16 64x2560         (327680)
#define OFF_OI  4816896    // out_in bf16 64x2560      (327680)
#define OFF_WE  5144576    // W_enc bf16 512x1024      (1048576)

static __device__ __forceinline__ bf16x8 cvt8(const float* p) {
    f32x4 a = *(const f32x4*)p;
    f32x4 b = *(const f32x4*)(p + 4);
    bf16x8 t;
    t[0] = (__bf16)a[0]; t[1] = (__bf16)a[1]; t[2] = (__bf16)a[2]; t[3] = (__bf16)a[3];
    t[4] = (__bf16)b[0]; t[5] = (__bf16)b[1]; t[6] = (__bf16)b[2]; t[7] = (__bf16)b[3];
    return t;
}

static __device__ __forceinline__ f32x4 mfma16(bf16x8 a, bf16x8 b, f32x4 c) {
    return __builtin_amdgcn_mfma_f32_16x16x32_bf16(a, b, c, 0, 0, 0);
}

// ---- fused init: [0,256) cvt_we | [256,320) prep | [320,328) decproj ---
__global__ __launch_bounds__(256) void k_init(const float* __restrict__ We,
                                              __bf16* __restrict__ we16,
                                              const int* __restrict__ tok,
                                              const float* __restrict__ hidden,
                                              const float* __restrict__ emb,
                                              __bf16* __restrict__ xh,
                                              __bf16* __restrict__ oi,
                                              const float* __restrict__ Wd,
                                              float* __restrict__ dp) {
    int bid = blockIdx.x, t = threadIdx.x;
    if (bid < 256) {
        // W_enc f32 -> bf16
        int base = (bid * 256 + t) * 8;
        *(bf16x8*)(we16 + base) = cvt8(We + base);
    } else if (bid < 320) {
        // embedding gather + hidden cvt
        int b = bid - 256;
        int tk = tok[b];
        #pragma unroll
        for (int j = 0; j < 2; ++j) {
            int e = t + 256 * j;
            float v = (tk == 0) ? 0.f : emb[tk * EMB + e];
            __bf16 h = (__bf16)v;
            xh[b * KXH + e] = h;                 // x = [emb | ctx | hid]
            oi[b * KOI + 2048 + e] = h;          // out_in = [nh | ctx | emb]
        }
        #pragma unroll
        for (int j = 0; j < 4; ++j) {
            int hidx = t + 256 * j;
            xh[b * KXH + 1536 + hidx] = (__bf16)hidden[b * DECH + hidx];
        }
    } else {
        // dec_proj = hidden @ W_dec^T via MFMA  [64,512]
        int bx = bid - 320;
        int w = t >> 6, l = t & 63, lo = l & 15, hi = l >> 4;
        int n = bx * 64 + w * 16 + lo;
        f32x4 acc[4];
        #pragma unroll
        for (int m = 0; m < 4; ++m) acc[m] = (f32x4){0.f, 0.f, 0.f, 0.f};
        for (int k0 = 0; k0 < DECH; k0 += 32) {
            int k = k0 + hi * 8;
            bf16x8 bf = cvt8(Wd + n * DECH + k);
            #pragma unroll
            for (int m = 0; m < 4; ++m) {
                bf16x8 af = cvt8(hidden + (m * 16 + lo) * DECH + k);
                acc[m] = mfma16(af, bf, acc[m]);
            }
        }
        #pragma unroll
        for (int m = 0; m < 4; ++m)
            #pragma unroll
            for (int ri = 0; ri < 4; ++ri) {
                int b = m * 16 + hi * 4 + ri;
                dp[b * ATTN + n] = acc[m][ri];
            }
    }
}

// ---- fused scores: tanh(enc@We^T + dp) . v  -> atomic scores[b][s] -----
// 256 blocks x 32 rows; wave covers 128 cols x 32 rows
__global__ __launch_bounds__(256) void k_scores(const float* __restrict__ enc,
                                                const __bf16* __restrict__ we16,
                                                const float* __restrict__ dp,
                                                const float* __restrict__ v,
                                                float* __restrict__ sc) {
    int t = threadIdx.x;
    int w = t >> 6, l = t & 63, lo = l & 15, hi = l >> 4;
    int r0 = blockIdx.x * 32;                 // 32 rows (s fixed, 32 b's)
    int cb = w * 128;                         // wave col strip
    f32x4 acc[2][8];
    #pragma unroll
    for (int m = 0; m < 2; ++m)
        #pragma unroll
        for (int f = 0; f < 8; ++f) acc[m][f] = (f32x4){0.f, 0.f, 0.f, 0.f};

    const float* arow0 = enc + (r0 + lo) * ENC2 + hi * 8;
    const float* arow1 = enc + (r0 + 16 + lo) * ENC2 + hi * 8;
    for (int k0 = 0; k0 < ENC2; k0 += 32) {
        bf16x8 a0 = cvt8(arow0 + k0);
        bf16x8 a1 = cvt8(arow1 + k0);
        #pragma unroll
        for (int f = 0; f < 8; ++f) {
            bf16x8 bf = *(const bf16x8*)(we16 + (cb + f * 16 + lo) * ENC2 + k0 + hi * 8);
            acc[0][f] = mfma16(a0, bf, acc[0][f]);
            acc[1][f] = mfma16(a1, bf, acc[1][f]);
        }
    }
    int s_ = r0 >> 6;
    float p[2][4] = {{0.f,0.f,0.f,0.f},{0.f,0.f,0.f,0.f}};
    #pragma unroll
    for (int f = 0; f < 8; ++f) {
        int c = cb + f * 16 + lo;
        float vv = v[c];
        #pragma unroll
        for (int m = 0; m < 2; ++m)
            #pragma unroll
            for (int ri = 0; ri < 4; ++ri) {
                int r = r0 + m * 16 + hi * 4 + ri;
                int b = r & 63;
                p[m][ri] += vv * tanhf(acc[m][f][ri] + dp[b * ATTN + c]);
            }
    }
    #pragma unroll
    for (int x = 1; x < 16; x <<= 1) {
        #pragma unroll
        for (int m = 0; m < 2; ++m)
            #pragma unroll
            for (int ri = 0; ri < 4; ++ri) p[m][ri] += __shfl_xor(p[m][ri], x);
    }
    if (lo == 0) {
        #pragma unroll
        for (int m = 0; m < 2; ++m)
            #pragma unroll
            for (int ri = 0; ri < 4; ++ri) {
                int r = r0 + m * 16 + hi * 4 + ri;
                atomicAdd(&sc[(r & 63) * SS + s_], p[m][ri]);
            }
    }
}

// ---- masked softmax over S per b ---------------------------------------
__global__ void k_softmax(const float* __restrict__ sc, const int* __restrict__ mask,
                          float* __restrict__ attn) {
    int b = blockIdx.x, l = threadIdx.x;      // 64 threads
    float s0 = sc[b * SS + l], s1 = sc[b * SS + 64 + l];
    if (mask[b * SS + l] == 0)      s0 = -3.0e38f;
    if (mask[b * SS + 64 + l] == 0) s1 = -3.0e38f;
    float m = fmaxf(s0, s1);
    #pragma unroll
    for (int x = 32; x >= 1; x >>= 1) m = fmaxf(m, __shfl_xor(m, x));
    float e0 = expf(s0 - m), e1 = expf(s1 - m);
    float sum = e0 + e1;
    #pragma unroll
    for (int x = 32; x >= 1; x >>= 1) sum += __shfl_xor(sum, x);
    float inv = 1.f / sum;
    attn[b * SS + l] = e0 * inv;
    attn[b * SS + 64 + l] = e1 * inv;
}

// ---- context partial: 256 blocks = (b, s-chunk of 32) ------------------
__global__ __launch_bounds__(256) void k_context(const float* __restrict__ enc,
                                                 const float* __restrict__ attn,
                                                 float* __restrict__ ctx) {
    int b = blockIdx.x & 63, sl = blockIdx.x >> 6, t = threadIdx.x;
    __shared__ float w[32];
    if (t < 32) w[t] = attn[b * SS + sl * 32 + t];
    __syncthreads();
    float acc[4] = {0.f, 0.f, 0.f, 0.f};
    for (int si = 0; si < 32; ++si) {
        int s = sl * 32 + si;
        float ws = w[si];
        const float* e = enc + (s * BB + b) * ENC2;
        #pragma unroll
        for (int j = 0; j < 4; ++j) acc[j] += ws * e[t + 256 * j];
    }
    #pragma unroll
    for (int j = 0; j < 4; ++j) atomicAdd(&ctx[b * ENC2 + t + 256 * j], acc[j]);
}

// ---- context finalize: f32 ctx -> bf16 into xh / oi --------------------
__global__ void k_ctxfin(const float* __restrict__ ctx,
                         __bf16* __restrict__ xh, __bf16* __restrict__ oi) {
    int b = blockIdx.x, t = threadIdx.x;
    #pragma unroll
    for (int j = 0; j < 4; ++j) {
        int e = t + 256 * j;
        __bf16 h = (__bf16)ctx[b * ENC2 + e];
        xh[b * KXH + 512 + e] = h;
        oi[b * KOI + 1024 + e] = h;
    }
}

// ---- gates GEMM: [64,4096] = xh @ [W_ih|W_hh]^T, split-K=4 -------------
__global__ __launch_bounds__(256) void k_gates(const __bf16* __restrict__ xh,
                                               const float* __restrict__ Wih,
                                               const float* __restrict__ Whh,
                                               float* __restrict__ gp) {
    int bx = blockIdx.x, ks = blockIdx.y;
    int t = threadIdx.x, w = t >> 6, l = t & 63, lo = l & 15, hi = l >> 4;
    int n = bx * 64 + w * 16 + lo;
    f32x4 acc[4];
    #pragma unroll
    for (int m = 0; m < 4; ++m) acc[m] = (f32x4){0.f, 0.f, 0.f, 0.f};
    int kend = ks * 640 + 640;
    for (int k0 = ks * 640; k0 < kend; k0 += 32) {
        int k = k0 + hi * 8;
        const float* bp = (k0 < 1536) ? (Wih + n * 1536 + k) : (Whh + n * 1024 + (k - 1536));
        bf16x8 bf = cvt8(bp);
        #pragma unroll
        for (int m = 0; m < 4; ++m) {
            bf16x8 af = *(const bf16x8*)(xh + (m * 16 + lo) * KXH + k);
            acc[m] = mfma16(af, bf, acc[m]);
        }
    }
    float* out = gp + ks * (BB * 4096);
    #pragma unroll
    for (int m = 0; m < 4; ++m)
        #pragma unroll
        for (int ri = 0; ri < 4; ++ri) {
            int row = m * 16 + hi * 4 + ri;
            out[row * 4096 + n] = acc[m][ri];
        }
}

// ---- LSTM pointwise ----------------------------------------------------
__global__ void k_lstm(const float* __restrict__ gp, const float* __restrict__ bih,
                       const float* __restrict__ bhh, const float* __restrict__ cell,
                       float* __restrict__ nh_out, float* __restrict__ nc_out,
                       __bf16* __restrict__ oi) {
    int b = blockIdx.x, t = threadIdx.x;
    #pragma unroll
    for (int j = 0; j < 4; ++j) {
        int h = t + 256 * j;
        float gi = 0.f, gf = 0.f, gg = 0.f, go = 0.f;
        #pragma unroll
        for (int ks = 0; ks < 4; ++ks) {
            const float* g = gp + ks * (BB * 4096) + b * 4096;
            gi += g[h]; gf += g[1024 + h]; gg += g[2048 + h]; go += g[3072 + h];
        }
        gi += bih[h] + bhh[h];
        gf += bih[1024 + h] + bhh[1024 + h];
        gg += bih[2048 + h] + bhh[2048 + h];
        go += bih[3072 + h] + bhh[3072 + h];
        float i_ = 1.f / (1.f + expf(-gi));
        float f_ = 1.f / (1.f + expf(-gf));
        float o_ = 1.f / (1.f + expf(-go));
        float g_ = tanhf(gg);
        float nc = f_ * cell[b * DECH + h] + i_ * g_;
        float nh = o_ * tanhf(nc);
        nc_out[b * DECH + h] = nc;
        nh_out[b * DECH + h] = nh;
        oi[b * KOI + h] = (__bf16)nh;
    }
}

// ---- output GEMM: [64,32000] = out_in @ W_out^T + b_out ----------------
__global__ __launch_bounds__(256) void k_out(const __bf16* __restrict__ oi,
                                             const float* __restrict__ Wo,
                                             const float* __restrict__ bo,
                                             float* __restrict__ out) {
    int bx = blockIdx.x;
    int t = threadIdx.x, w = t >> 6, l = t & 63, lo = l & 15, hi = l >> 4;
    int n = bx * 64 + w * 16 + lo;
    f32x4 acc[4];
    #pragma unroll
    for (int m = 0; m < 4; ++m) acc[m] = (f32x4){0.f, 0.f, 0.f, 0.f};
    const float* wrow = Wo + (long)n * KOI;
    for (int k0 = 0; k0 < KOI; k0 += 32) {
        int k = k0 + hi * 8;
        bf16x8 bf = cvt8(wrow + k);
        #pragma unroll
        for (int m = 0; m < 4; ++m) {
            bf16x8 af = *(const bf16x8*)(oi + (m * 16 + lo) * KOI + k);
            acc[m] = mfma16(af, bf, acc[m]);
        }
    }
    float bb = bo[n];
    #pragma unroll
    for (int m = 0; m < 4; ++m)
        #pragma unroll
        for (int ri = 0; ri < 4; ++ri) {
            int row = m * 16 + hi * 4 + ri;
            out[row * VOCAB + n] = acc[m][ri] + bb;
        }
}

extern "C" void kernel_launch(void* const* d_in, const int* in_sizes, int n_in,
                              void* d_out, int out_size, void* d_ws, size_t ws_size,
                              hipStream_t stream) {
    const int*   tok    = (const int*)d_in[0];
    const float* hidden = (const float*)d_in[1];
    const float* cell   = (const float*)d_in[2];
    const float* enc    = (const float*)d_in[3];
    const int*   mask   = (const int*)d_in[4];
    const float* emb    = (const float*)d_in[5];
    const float* We     = (const float*)d_in[6];
    const float* Wd     = (const float*)d_in[7];
    const float* v      = (const float*)d_in[8];
    const float* Wih    = (const float*)d_in[9];
    const float* Whh    = (const float*)d_in[10];
    const float* bih    = (const float*)d_in[11];
    const float* bhh    = (const float*)d_in[12];
    const float* Wo     = (const float*)d_in[13];
    const float* bo     = (const float*)d_in[14];

    char* ws = (char*)d_ws;
    float*  sc   = (float*)(ws + OFF_SC);
    float*  ctx  = (float*)(ws + OFF_CTX);
    float*  gp   = (float*)(ws + OFF_GP);
    __bf16* xh   = (__bf16*)(ws + OFF_XH);
    __bf16* oi   = (__bf16*)(ws + OFF_OI);
    __bf16* we16 = (__bf16*)(ws + OFF_WE);
    float*  dp   = (float*)(ws + OFF_WE + 1048576);   // reuse tail: 64x512 f32

    float* out_logits = (float*)d_out;                 // [64,32000]
    float* nh   = out_logits + BB * VOCAB;             // [64,1024]
    float* nc   = nh + BB * DECH;                      // [64,1024]
    float* attn = nc + BB * DECH;                      // [64,128]

    hipMemsetAsync(sc, 0, (BB * SS + BB * ENC2) * sizeof(float), stream);
    k_init<<<328, 256, 0, stream>>>(We, we16, tok, hidden, emb, xh, oi, Wd, dp);
    k_scores<<<256, 256, 0, stream>>>(enc, we16, dp, v, sc);
    k_softmax<<<BB, 64, 0, stream>>>(sc, mask, attn);
    k_context<<<256, 256, 0, stream>>>(enc, attn, ctx);
    k_ctxfin<<<BB, 256, 0, stream>>>(ctx, xh, oi);
    dim3 g2(64, 4);
    k_gates<<<g2, 256, 0, stream>>>(xh, Wih, Whh, gp);
    k_lstm<<<BB, 256, 0, stream>>>(gp, bih, bhh, cell, nh, nc, oi);
    k_out<<<500, 256, 0, stream>>>(oi, Wo, bo, out_logits);
}